// Round 3
// baseline (536.951 us; speedup 1.0000x reference)
//
#include <hip/hip_runtime.h>

// ConvAttention2d: B=4, DIM=384, HEADS=8, DH=64, INNER=512, H=W=56, KS=3
// fp32 end-to-end (reference dtype), correctness-first VALU GEMMs.
// qkv = x @ [Wq;Wkv] -> 3x3 neighborhood attention -> out = ao @ Wo + bo

#define HW 3136
#define WIMG 56
#define QKV_CH 1536
#define SCALE 0.125f

// ---------------------------------------------------------------------------
// GEMM1: qkv[b][o][s] = sum_c Wrow(o)[c] * x[b][c][s]
//   o in [0,512): Wq row o ; o in [512,1536): Wkv row o-512
// Thread: 4 adjacent s (float4), 8 adjacent o. grid (4, 192, 4), block 256.
// ---------------------------------------------------------------------------
__global__ __launch_bounds__(256) void gemm_qkv_f(
    const float* __restrict__ x,    // (4,384,3136)
    const float* __restrict__ Wq,   // (512,384)
    const float* __restrict__ Wkv,  // (1024,384)
    float* __restrict__ qkv)        // (4,1536,3136)
{
    const int s = (blockIdx.x * 256 + threadIdx.x) * 4;
    if (s >= HW) return;
    const int o0 = blockIdx.y * 8;          // 0..1528; 512 boundary is 8-aligned
    const int b  = blockIdx.z;
    const float* w = (o0 < 512) ? (Wq + (size_t)o0 * 384)
                                : (Wkv + (size_t)(o0 - 512) * 384);
    const float* xb = x + (size_t)b * 384 * HW + s;

    float acc[8][4];
#pragma unroll
    for (int o = 0; o < 8; o++)
#pragma unroll
        for (int i = 0; i < 4; i++) acc[o][i] = 0.f;

#pragma unroll 4
    for (int k = 0; k < 384; k++) {
        const float4 xv = *reinterpret_cast<const float4*>(xb + (size_t)k * HW);
#pragma unroll
        for (int o = 0; o < 8; o++) {
            const float wv = w[(size_t)o * 384 + k];
            acc[o][0] += xv.x * wv;
            acc[o][1] += xv.y * wv;
            acc[o][2] += xv.z * wv;
            acc[o][3] += xv.w * wv;
        }
    }

    float* op = qkv + (size_t)b * QKV_CH * HW + (size_t)o0 * HW + s;
#pragma unroll
    for (int o = 0; o < 8; o++) {
        float4 r; r.x = acc[o][0]; r.y = acc[o][1]; r.z = acc[o][2]; r.w = acc[o][3];
        *reinterpret_cast<float4*>(op + (size_t)o * HW) = r;
    }
}

// ---------------------------------------------------------------------------
// Neighborhood attention, fp32. Per (b,h,s): 9-tap QK dots, softmax where
// padded taps keep logit exactly 0 (zero-pad unfold semantics) and count in
// the denominator; their v-contribution is zeroed. One wave per 64 pixels.
// ---------------------------------------------------------------------------
__global__ __launch_bounds__(64) void natt_f(
    const float* __restrict__ qkv,  // (4,1536,3136)
    float* __restrict__ ao)         // (4,512,3136)
{
    const int lane = threadIdx.x;
    const int s = blockIdx.x * 64 + lane;
    const int h = blockIdx.y, b = blockIdx.z;
    const int y = s / WIMG, xx = s % WIMG;

    const float* qp = qkv + (size_t)b * QKV_CH * HW + (size_t)(h * 64) * HW + s;
    const float* kp = qp + (size_t)512 * HW;
    const float* vp = qp + (size_t)1024 * HW;

    int   offc[9];
    float msk[9];
#pragma unroll
    for (int ty = 0; ty < 3; ty++) {
#pragma unroll
        for (int tx = 0; tx < 3; tx++) {
            const int tap = ty * 3 + tx;
            const int ny = y + ty - 1, nx = xx + tx - 1;
            const bool v = (ny >= 0) && (ny < WIMG) && (nx >= 0) && (nx < WIMG);
            offc[tap] = v ? ((ty - 1) * WIMG + (tx - 1)) : 0;  // invalid -> safe self-offset
            msk[tap]  = v ? 1.f : 0.f;
        }
    }

    float dots[9];
#pragma unroll
    for (int tp = 0; tp < 9; tp++) dots[tp] = 0.f;

#pragma unroll 4
    for (int d = 0; d < 64; d++) {
        const float qv = qp[(size_t)d * HW];
#pragma unroll
        for (int tp = 0; tp < 9; tp++) {
            dots[tp] += qv * kp[(size_t)d * HW + offc[tp]] * msk[tp];
        }
    }

    float mx = -1e30f;
#pragma unroll
    for (int tp = 0; tp < 9; tp++) {
        dots[tp] *= SCALE;               // masked taps stay exactly 0
        mx = fmaxf(mx, dots[tp]);
    }
    float se = 0.f, w9[9];
#pragma unroll
    for (int tp = 0; tp < 9; tp++) { w9[tp] = __expf(dots[tp] - mx); se += w9[tp]; }
    const float inv = 1.f / se;
#pragma unroll
    for (int tp = 0; tp < 9; tp++) w9[tp] *= inv * msk[tp];  // padded v contributes 0

    float* aop = ao + (size_t)b * 512 * HW + (size_t)(h * 64) * HW + s;
#pragma unroll 4
    for (int d = 0; d < 64; d++) {
        float o = 0.f;
#pragma unroll
        for (int tp = 0; tp < 9; tp++) {
            o += w9[tp] * vp[(size_t)d * HW + offc[tp]];
        }
        aop[(size_t)d * HW] = o;
    }
}

// ---------------------------------------------------------------------------
// GEMM3: out[b][o][s] = sum_c Wo[o][c] * ao[b][c][s] + bo[o]
// Thread: 4 s, 8 o. grid (4, 48, 4), block 256.
// ---------------------------------------------------------------------------
__global__ __launch_bounds__(256) void gemm_out_f(
    const float* __restrict__ ao,   // (4,512,3136)
    const float* __restrict__ Wo,   // (384,512)
    const float* __restrict__ bo,   // (384)
    float* __restrict__ out)        // (4,384,3136)
{
    const int s = (blockIdx.x * 256 + threadIdx.x) * 4;
    if (s >= HW) return;
    const int o0 = blockIdx.y * 8;          // 0..376
    const int b  = blockIdx.z;
    const float* w  = Wo + (size_t)o0 * 512;
    const float* ab = ao + (size_t)b * 512 * HW + s;

    float acc[8][4];
#pragma unroll
    for (int o = 0; o < 8; o++)
#pragma unroll
        for (int i = 0; i < 4; i++) acc[o][i] = 0.f;

#pragma unroll 4
    for (int k = 0; k < 512; k++) {
        const float4 xv = *reinterpret_cast<const float4*>(ab + (size_t)k * HW);
#pragma unroll
        for (int o = 0; o < 8; o++) {
            const float wv = w[(size_t)o * 512 + k];
            acc[o][0] += xv.x * wv;
            acc[o][1] += xv.y * wv;
            acc[o][2] += xv.z * wv;
            acc[o][3] += xv.w * wv;
        }
    }

    float* op = out + (size_t)b * 384 * HW + (size_t)o0 * HW + s;
#pragma unroll
    for (int o = 0; o < 8; o++) {
        const float bb = bo[o0 + o];
        float4 r;
        r.x = acc[o][0] + bb; r.y = acc[o][1] + bb;
        r.z = acc[o][2] + bb; r.w = acc[o][3] + bb;
        *reinterpret_cast<float4*>(op + (size_t)o * HW) = r;
    }
}

extern "C" void kernel_launch(void* const* d_in, const int* in_sizes, int n_in,
                              void* d_out, int out_size, void* d_ws, size_t ws_size,
                              hipStream_t stream) {
    const float* x   = (const float*)d_in[0];
    const float* Wq  = (const float*)d_in[1];
    const float* Wkv = (const float*)d_in[2];
    const float* Wo  = (const float*)d_in[3];
    const float* bo  = (const float*)d_in[4];
    float* out = (float*)d_out;

    float* qkv = (float*)d_ws;                       // 4*1536*3136 f32 = 77.1 MB
    float* ao  = qkv + (size_t)4 * QKV_CH * HW;      // 4*512*3136  f32 = 25.7 MB

    gemm_qkv_f<<<dim3(4, 192, 4), 256, 0, stream>>>(x, Wq, Wkv, qkv);
    natt_f    <<<dim3(49,  8, 4),  64, 0, stream>>>(qkv, ao);
    gemm_out_f<<<dim3(4,  48, 4), 256, 0, stream>>>(ao, Wo, bo, out);
}

// Round 4
// 236.606 us; speedup vs baseline: 2.2694x; 2.2694x over previous
//
#include <hip/hip_runtime.h>

// ConvAttention2d: B=4, DIM=384, HEADS=8, DH=64, INNER=512, H=W=56, KS=3
// fp32 in/out. Internals: bf16 MFMA GEMMs (fp32 accum), bf16 qkv/ao buffers.
// qkv = x @ [Wq;Wkv] -> 3x3 neighborhood attention -> out = ao @ Wo + bo

#define HW 3136
#define WIMG 56
#define QKV_CH 1536
#define SCALE 0.125f

typedef __bf16 bf16x8_t __attribute__((ext_vector_type(8)));
typedef float f32x4_t __attribute__((ext_vector_type(4)));

__device__ __forceinline__ float bf2f(unsigned short u) {
    return __uint_as_float(((unsigned int)u) << 16);
}
__device__ __forceinline__ unsigned short f2bf(float f) {
    unsigned int u = __float_as_uint(f);
    u += 0x7FFFu + ((u >> 16) & 1u);   // round-to-nearest-even
    return (unsigned short)(u >> 16);
}
// 16B-granule rotation: breaks bank serialization for strided row access.
__device__ __forceinline__ int gpos(int g, int row) { return (g + ((row >> 1) & 3)) & 3; }

// ---------------------------------------------------------------------------
// f32 -> bf16 bulk convert (n4 float4s)
// ---------------------------------------------------------------------------
__global__ __launch_bounds__(256) void cvt_bf16(
    const float* __restrict__ in, unsigned short* __restrict__ out, int n4)
{
    const int i = blockIdx.x * 256 + threadIdx.x;
    if (i >= n4) return;
    const float4 v = reinterpret_cast<const float4*>(in)[i];
    uint2 u;
    u.x = (unsigned int)f2bf(v.x) | ((unsigned int)f2bf(v.y) << 16);
    u.y = (unsigned int)f2bf(v.z) | ((unsigned int)f2bf(v.w) << 16);
    reinterpret_cast<uint2*>(out)[i] = u;
}

// ---------------------------------------------------------------------------
// MFMA GEMM: out[o][s] = sum_c W[o][c] * X[c][s]   (bf16 in, fp32 acc)
// Tile: 128 o x 64 s, K-step 32. Block 256 (4 waves); wave w: 32 o rows.
// A_lds[128][32], B_lds[64][32] bf16, granule-swizzled.
// GEMM1: W=(1536,384) K=384, out bf16.  GEMM3: W=(384,512) K=512, out f32+bias.
// ---------------------------------------------------------------------------
template <int K, bool OUT_F32>
__global__ __launch_bounds__(256) void gemm_mfma(
    const unsigned short* __restrict__ Xb,   // (B, K, HW) bf16
    const unsigned short* __restrict__ Wb,   // (M, K) bf16
    const float* __restrict__ bias,          // (M) or nullptr pattern via OUT_F32
    unsigned short* __restrict__ out_bf,     // (B, M, HW) bf16 (GEMM1)
    float* __restrict__ out_f,               // (B, M, HW) f32  (GEMM3)
    int M)
{
    __shared__ __align__(16) unsigned short A_lds[128 * 32];
    __shared__ __align__(16) unsigned short B_lds[64 * 32];

    const int s0 = blockIdx.x * 64;
    const int o0 = blockIdx.y * 128;
    const int b  = blockIdx.z;
    const int t  = threadIdx.x;
    const int lane = t & 63, w = t >> 6;
    const int quad = lane >> 4, mrow = lane & 15;

    // A staging: thread t -> rows (t>>2) and (t>>2)+64, granule t&3
    const int ar = t >> 2, ag = t & 3;
    // B staging: thread t -> s-row t&63, granule t>>6 (8 strided c loads)
    const int bs = t & 63, bg = t >> 6;

    const unsigned short* xp = Xb + (size_t)b * K * HW + s0 + bs;
    const unsigned short* wr0 = Wb + (size_t)(o0 + ar) * K;
    const unsigned short* wr1 = Wb + (size_t)(o0 + 64 + ar) * K;

    f32x4_t acc[2][4];
#pragma unroll
    for (int m = 0; m < 2; m++)
#pragma unroll
        for (int nt = 0; nt < 4; nt++) acc[m][nt] = (f32x4_t){0.f, 0.f, 0.f, 0.f};

    for (int k0 = 0; k0 < K; k0 += 32) {
        const uint4 a0 = *reinterpret_cast<const uint4*>(wr0 + k0 + ag * 8);
        const uint4 a1 = *reinterpret_cast<const uint4*>(wr1 + k0 + ag * 8);
        __align__(16) unsigned short bv[8];
#pragma unroll
        for (int j = 0; j < 8; j++)
            bv[j] = xp[(size_t)(k0 + bg * 8 + j) * HW];

        __syncthreads();   // previous iteration's LDS reads complete
        *reinterpret_cast<uint4*>(&A_lds[ar * 32 + gpos(ag, ar) * 8]) = a0;
        *reinterpret_cast<uint4*>(&A_lds[(64 + ar) * 32 + gpos(ag, 64 + ar) * 8]) = a1;
        *reinterpret_cast<uint4*>(&B_lds[bs * 32 + gpos(bg, bs) * 8]) =
            *reinterpret_cast<const uint4*>(bv);
        __syncthreads();

        bf16x8_t bfr[4];
#pragma unroll
        for (int nt = 0; nt < 4; nt++) {
            const int srow = nt * 16 + mrow;
            bfr[nt] = *reinterpret_cast<const bf16x8_t*>(&B_lds[srow * 32 + gpos(quad, srow) * 8]);
        }
#pragma unroll
        for (int m = 0; m < 2; m++) {
            const int orow = w * 32 + m * 16 + mrow;
            const bf16x8_t af = *reinterpret_cast<const bf16x8_t*>(&A_lds[orow * 32 + gpos(quad, orow) * 8]);
#pragma unroll
            for (int nt = 0; nt < 4; nt++)
                acc[m][nt] = __builtin_amdgcn_mfma_f32_16x16x32_bf16(af, bfr[nt], acc[m][nt], 0, 0, 0);
        }
    }

#pragma unroll
    for (int m = 0; m < 2; m++)
#pragma unroll
        for (int nt = 0; nt < 4; nt++)
#pragma unroll
            for (int r = 0; r < 4; r++) {
                const int oo = o0 + w * 32 + m * 16 + quad * 4 + r;
                const int ss = s0 + nt * 16 + mrow;
                if (OUT_F32) {
                    out_f[(size_t)b * M * HW + (size_t)oo * HW + ss] = acc[m][nt][r] + bias[oo];
                } else {
                    out_bf[(size_t)b * M * HW + (size_t)oo * HW + ss] = f2bf(acc[m][nt][r]);
                }
            }
}

// ---------------------------------------------------------------------------
// Neighborhood attention (bf16 qkv, fp32 math). Block 256 = 4 waves; wave w
// handles d in [w*16, w*16+16). Partial dots reduced via LDS; padded taps
// keep logit exactly 0 (zero-pad unfold) and stay in the denominator.
// ---------------------------------------------------------------------------
__global__ __launch_bounds__(256) void natt(
    const unsigned short* __restrict__ qkv,  // (4,1536,3136) bf16
    unsigned short* __restrict__ ao)         // (4,512,3136) bf16
{
    __shared__ float dred[9][4][64];

    const int t = threadIdx.x, lane = t & 63, w = t >> 6;
    const int s = blockIdx.x * 64 + lane;
    const int h = blockIdx.y, b = blockIdx.z;
    const int y = s / WIMG, xx = s % WIMG;

    const unsigned short* base = qkv + (size_t)b * QKV_CH * HW + (size_t)(h * 64) * HW + s;

    int   offc[9];
    float msk[9];
#pragma unroll
    for (int ty = 0; ty < 3; ty++)
#pragma unroll
        for (int tx = 0; tx < 3; tx++) {
            const int tap = ty * 3 + tx;
            const int ny = y + ty - 1, nx = xx + tx - 1;
            const bool v = (ny >= 0) && (ny < WIMG) && (nx >= 0) && (nx < WIMG);
            offc[tap] = v ? ((ty - 1) * WIMG + (tx - 1)) : 0;
            msk[tap]  = v ? 1.f : 0.f;
        }

    float dots[9];
#pragma unroll
    for (int tp = 0; tp < 9; tp++) dots[tp] = 0.f;

#pragma unroll 4
    for (int dd = 0; dd < 16; dd++) {
        const int d = w * 16 + dd;
        const float qv = bf2f(base[(size_t)d * HW]);
#pragma unroll
        for (int tp = 0; tp < 9; tp++)
            dots[tp] += qv * bf2f(base[(size_t)(512 + d) * HW + offc[tp]]) * msk[tp];
    }
#pragma unroll
    for (int tp = 0; tp < 9; tp++) dred[tp][w][lane] = dots[tp];
    __syncthreads();

    float mx = -1e30f, dt[9];
#pragma unroll
    for (int tp = 0; tp < 9; tp++) {
        dt[tp] = (dred[tp][0][lane] + dred[tp][1][lane] +
                  dred[tp][2][lane] + dred[tp][3][lane]) * SCALE;
        mx = fmaxf(mx, dt[tp]);
    }
    float se = 0.f, w9[9];
#pragma unroll
    for (int tp = 0; tp < 9; tp++) { w9[tp] = __expf(dt[tp] - mx); se += w9[tp]; }
    const float inv = 1.f / se;
#pragma unroll
    for (int tp = 0; tp < 9; tp++) w9[tp] *= inv * msk[tp];

    unsigned short* aop = ao + (size_t)b * 512 * HW + (size_t)(h * 64) * HW + s;
#pragma unroll 4
    for (int dd = 0; dd < 16; dd++) {
        const int d = w * 16 + dd;
        float o = 0.f;
#pragma unroll
        for (int tp = 0; tp < 9; tp++)
            o += w9[tp] * bf2f(base[(size_t)(1024 + d) * HW + offc[tp]]);
        aop[(size_t)d * HW] = f2bf(o);
    }
}

extern "C" void kernel_launch(void* const* d_in, const int* in_sizes, int n_in,
                              void* d_out, int out_size, void* d_ws, size_t ws_size,
                              hipStream_t stream) {
    const float* x   = (const float*)d_in[0];
    const float* Wq  = (const float*)d_in[1];
    const float* Wkv = (const float*)d_in[2];
    const float* Wo  = (const float*)d_in[3];
    const float* bo  = (const float*)d_in[4];
    float* out = (float*)d_out;

    // ws layout (bf16 elements)
    unsigned short* xb   = (unsigned short*)d_ws;                 // 4*384*3136  = 4,816,896
    unsigned short* wb   = xb + (size_t)4 * 384 * HW;             // 1536*384    =   589,824
    unsigned short* wob  = wb + (size_t)1536 * 384;               // 384*512     =   196,608
    unsigned short* qkvb = wob + (size_t)384 * 512;               // 4*1536*3136 = 19,267,584
    unsigned short* aob  = qkvb + (size_t)4 * QKV_CH * HW;        // 4*512*3136  =  6,422,528
    // total ~62.6 MB bf16

    cvt_bf16<<<dim3(4704), 256, 0, stream>>>(x, xb, 1204224);            // 4816896/4
    cvt_bf16<<<dim3(192),  256, 0, stream>>>(Wq, wb, 49152);             // 196608/4
    cvt_bf16<<<dim3(384),  256, 0, stream>>>(Wkv, wb + 196608, 98304);   // 393216/4
    cvt_bf16<<<dim3(192),  256, 0, stream>>>(Wo, wob, 49152);            // 196608/4

    gemm_mfma<384, false><<<dim3(49, 12, 4), 256, 0, stream>>>(
        xb, wb, nullptr, qkvb, nullptr, QKV_CH);
    natt<<<dim3(49, 8, 4), 256, 0, stream>>>(qkvb, aob);
    gemm_mfma<512, true><<<dim3(49, 3, 4), 256, 0, stream>>>(
        aob, wob, bo, nullptr, out, 384);
}

// Round 5
// 157.893 us; speedup vs baseline: 3.4007x; 1.4985x over previous
//
#include <hip/hip_runtime.h>

// ConvAttention2d: B=4, DIM=384, HEADS=8, DH=64, INNER=512, H=W=56, KS=3
// fp32 in/out. Internals: bf16 MFMA GEMMs (fp32 accum), bf16 qkv/ao buffers.
// qkv = x @ [Wq;Wkv] -> 3x3 neighborhood attention -> out = ao @ Wo + bo

#define HW 3136
#define WIMG 56
#define QKV_CH 1536
#define SCALE 0.125f
#define SLEN 200   // LDS row stride (ushorts) for 192-elem halo rows

typedef __bf16 bf16x8_t __attribute__((ext_vector_type(8)));
typedef float f32x4_t __attribute__((ext_vector_type(4)));

__device__ __forceinline__ float bf2f(unsigned short u) {
    return __uint_as_float(((unsigned int)u) << 16);
}
__device__ __forceinline__ unsigned short f2bf(float f) {
    unsigned int u = __float_as_uint(f);
    u += 0x7FFFu + ((u >> 16) & 1u);   // round-to-nearest-even
    return (unsigned short)(u >> 16);
}
// 16B-granule rotation: breaks bank serialization for strided row access.
__device__ __forceinline__ int gpos(int g, int row) { return (g + ((row >> 1) & 3)) & 3; }

// ---------------------------------------------------------------------------
// f32 -> bf16 bulk convert (n4 float4s)
// ---------------------------------------------------------------------------
__global__ __launch_bounds__(256) void cvt_bf16(
    const float* __restrict__ in, unsigned short* __restrict__ out, int n4)
{
    const int i = blockIdx.x * 256 + threadIdx.x;
    if (i >= n4) return;
    const float4 v = reinterpret_cast<const float4*>(in)[i];
    uint2 u;
    u.x = (unsigned int)f2bf(v.x) | ((unsigned int)f2bf(v.y) << 16);
    u.y = (unsigned int)f2bf(v.z) | ((unsigned int)f2bf(v.w) << 16);
    reinterpret_cast<uint2*>(out)[i] = u;
}

// ---------------------------------------------------------------------------
// MFMA GEMM: out[o][s] = sum_c W[o][c] * X[c][s]   (bf16 in, fp32 acc)
// Tile: 128 o x 64 s, K-step 32. Block 256 (4 waves); wave w: 32 o rows.
// ---------------------------------------------------------------------------
template <int K, bool OUT_F32>
__global__ __launch_bounds__(256) void gemm_mfma(
    const unsigned short* __restrict__ Xb,   // (B, K, HW) bf16
    const unsigned short* __restrict__ Wb,   // (M, K) bf16
    const float* __restrict__ bias,          // (M), used when OUT_F32
    unsigned short* __restrict__ out_bf,     // (B, M, HW) bf16 (GEMM1)
    float* __restrict__ out_f,               // (B, M, HW) f32  (GEMM3)
    int M)
{
    __shared__ __align__(16) unsigned short A_lds[128 * 32];
    __shared__ __align__(16) unsigned short B_lds[64 * 32];

    const int s0 = blockIdx.x * 64;
    const int o0 = blockIdx.y * 128;
    const int b  = blockIdx.z;
    const int t  = threadIdx.x;
    const int lane = t & 63, w = t >> 6;
    const int quad = lane >> 4, mrow = lane & 15;

    const int ar = t >> 2, ag = t & 3;
    const int bs = t & 63, bg = t >> 6;

    const unsigned short* xp = Xb + (size_t)b * K * HW + s0 + bs;
    const unsigned short* wr0 = Wb + (size_t)(o0 + ar) * K;
    const unsigned short* wr1 = Wb + (size_t)(o0 + 64 + ar) * K;

    f32x4_t acc[2][4];
#pragma unroll
    for (int m = 0; m < 2; m++)
#pragma unroll
        for (int nt = 0; nt < 4; nt++) acc[m][nt] = (f32x4_t){0.f, 0.f, 0.f, 0.f};

    for (int k0 = 0; k0 < K; k0 += 32) {
        const uint4 a0 = *reinterpret_cast<const uint4*>(wr0 + k0 + ag * 8);
        const uint4 a1 = *reinterpret_cast<const uint4*>(wr1 + k0 + ag * 8);
        __align__(16) unsigned short bv[8];
#pragma unroll
        for (int j = 0; j < 8; j++)
            bv[j] = xp[(size_t)(k0 + bg * 8 + j) * HW];

        __syncthreads();
        *reinterpret_cast<uint4*>(&A_lds[ar * 32 + gpos(ag, ar) * 8]) = a0;
        *reinterpret_cast<uint4*>(&A_lds[(64 + ar) * 32 + gpos(ag, 64 + ar) * 8]) = a1;
        *reinterpret_cast<uint4*>(&B_lds[bs * 32 + gpos(bg, bs) * 8]) =
            *reinterpret_cast<const uint4*>(bv);
        __syncthreads();

        bf16x8_t bfr[4];
#pragma unroll
        for (int nt = 0; nt < 4; nt++) {
            const int srow = nt * 16 + mrow;
            bfr[nt] = *reinterpret_cast<const bf16x8_t*>(&B_lds[srow * 32 + gpos(quad, srow) * 8]);
        }
#pragma unroll
        for (int m = 0; m < 2; m++) {
            const int orow = w * 32 + m * 16 + mrow;
            const bf16x8_t af = *reinterpret_cast<const bf16x8_t*>(&A_lds[orow * 32 + gpos(quad, orow) * 8]);
#pragma unroll
            for (int nt = 0; nt < 4; nt++)
                acc[m][nt] = __builtin_amdgcn_mfma_f32_16x16x32_bf16(af, bfr[nt], acc[m][nt], 0, 0, 0);
        }
    }

#pragma unroll
    for (int m = 0; m < 2; m++)
#pragma unroll
        for (int nt = 0; nt < 4; nt++)
#pragma unroll
            for (int r = 0; r < 4; r++) {
                const int oo = o0 + w * 32 + m * 16 + quad * 4 + r;
                const int ss = s0 + nt * 16 + mrow;
                if (OUT_F32) {
                    out_f[(size_t)b * M * HW + (size_t)oo * HW + ss] = acc[m][nt][r] + bias[oo];
                } else {
                    out_bf[(size_t)b * M * HW + (size_t)oo * HW + ss] = f2bf(acc[m][nt][r]);
                }
            }
}

// ---------------------------------------------------------------------------
// Neighborhood attention v2: LDS halo staging.
// Block 256 = 4 waves, tile = 64 pixels x 1 head. K/V halo [s0-64, s0+128)
// x 64ch staged via uint4; wave w computes d in [w*16, w*16+16); dots reduced
// through LDS (overlaid on dead K tile). Padded taps: logit exactly 0, stay
// in denominator, v-contribution zeroed (zero-pad unfold semantics).
// ---------------------------------------------------------------------------
__global__ __launch_bounds__(256) void natt2(
    const unsigned short* __restrict__ qkv,  // (4,1536,3136) bf16
    unsigned short* __restrict__ ao)         // (4,512,3136) bf16
{
    __shared__ __align__(16) unsigned short smem[2 * 64 * SLEN]; // Kl | Vl
    unsigned short* Kl = smem;
    unsigned short* Vl = smem + 64 * SLEN;
    float* dred = reinterpret_cast<float*>(smem);  // overlays Kl after dots

    const int t = threadIdx.x, lane = t & 63, w = t >> 6;
    const int s0 = blockIdx.x * 64;
    const int s  = s0 + lane;
    const int h  = blockIdx.y, b = blockIdx.z;
    const int y  = s / WIMG, xx = s % WIMG;

    const size_t hbase = (size_t)b * QKV_CH * HW + (size_t)(h * 64) * HW;
    const unsigned short* kg = qkv + hbase + (size_t)512 * HW;
    const unsigned short* vg = qkv + hbase + (size_t)1024 * HW;

    // Stage K/V: 64 channels x 24 uint4 chunks each (flat-index cooperative).
#pragma unroll
    for (int i = 0; i < 6; i++) {
        const int f = i * 256 + t;        // 0..1535
        const int d = f / 24, j = f % 24;
        int g = s0 - 64 + j * 8;
        g = min(max(g, 0), HW - 8);       // clamped slots only read by masked taps
        const uint4 k4 = *reinterpret_cast<const uint4*>(kg + (size_t)d * HW + g);
        const uint4 v4 = *reinterpret_cast<const uint4*>(vg + (size_t)d * HW + g);
        *reinterpret_cast<uint4*>(&Kl[d * SLEN + j * 8]) = k4;
        *reinterpret_cast<uint4*>(&Vl[d * SLEN + j * 8]) = v4;
    }

    int   off9[9];
    float msk[9];
#pragma unroll
    for (int ty = 0; ty < 3; ty++)
#pragma unroll
        for (int tx = 0; tx < 3; tx++) {
            const int tap = ty * 3 + tx;
            const int ny = y + ty - 1, nx = xx + tx - 1;
            const bool v = (ny >= 0) && (ny < WIMG) && (nx >= 0) && (nx < WIMG);
            off9[tap] = v ? ((ty - 1) * WIMG + (tx - 1)) : 0;  // invalid -> self
            msk[tap]  = v ? 1.f : 0.f;
        }

    __syncthreads();

    // Dots: wave w handles 16 channels; q direct from global (coalesced).
    const unsigned short* qp = qkv + hbase + s;
    float dots[9];
#pragma unroll
    for (int tp = 0; tp < 9; tp++) dots[tp] = 0.f;
#pragma unroll 4
    for (int dd = 0; dd < 16; dd++) {
        const int d = w * 16 + dd;
        const float qv = bf2f(qp[(size_t)d * HW]);
        const int bi = d * SLEN + lane + 64;
#pragma unroll
        for (int tp = 0; tp < 9; tp++)
            dots[tp] += qv * bf2f(Kl[bi + off9[tp]]);   // mask applied after sum
    }

    __syncthreads();   // all waves done reading Kl -> safe to overlay dred
#pragma unroll
    for (int tp = 0; tp < 9; tp++) dred[(tp * 4 + w) * 64 + lane] = dots[tp];
    __syncthreads();

    float mx = -1e30f, dt[9];
#pragma unroll
    for (int tp = 0; tp < 9; tp++) {
        const float sum = dred[(tp * 4 + 0) * 64 + lane] + dred[(tp * 4 + 1) * 64 + lane] +
                          dred[(tp * 4 + 2) * 64 + lane] + dred[(tp * 4 + 3) * 64 + lane];
        dt[tp] = msk[tp] * (sum * SCALE);   // masked taps: logit exactly 0
        mx = fmaxf(mx, dt[tp]);
    }
    float se = 0.f, w9[9];
#pragma unroll
    for (int tp = 0; tp < 9; tp++) { w9[tp] = __expf(dt[tp] - mx); se += w9[tp]; }
    const float inv = 1.f / se;
#pragma unroll
    for (int tp = 0; tp < 9; tp++) w9[tp] *= inv * msk[tp];  // masked v contributes 0

    unsigned short* aop = ao + (size_t)b * 512 * HW + (size_t)(h * 64) * HW + s;
#pragma unroll 4
    for (int dd = 0; dd < 16; dd++) {
        const int d = w * 16 + dd;
        const int bi = d * SLEN + lane + 64;
        float o = 0.f;
#pragma unroll
        for (int tp = 0; tp < 9; tp++)
            o += w9[tp] * bf2f(Vl[bi + off9[tp]]);
        aop[(size_t)d * HW] = f2bf(o);
    }
}

extern "C" void kernel_launch(void* const* d_in, const int* in_sizes, int n_in,
                              void* d_out, int out_size, void* d_ws, size_t ws_size,
                              hipStream_t stream) {
    const float* x   = (const float*)d_in[0];
    const float* Wq  = (const float*)d_in[1];
    const float* Wkv = (const float*)d_in[2];
    const float* Wo  = (const float*)d_in[3];
    const float* bo  = (const float*)d_in[4];
    float* out = (float*)d_out;

    // ws layout (bf16 elements)
    unsigned short* xb   = (unsigned short*)d_ws;                 // 4*384*3136
    unsigned short* wb   = xb + (size_t)4 * 384 * HW;             // 1536*384
    unsigned short* wob  = wb + (size_t)1536 * 384;               // 384*512
    unsigned short* qkvb = wob + (size_t)384 * 512;               // 4*1536*3136
    unsigned short* aob  = qkvb + (size_t)4 * QKV_CH * HW;        // 4*512*3136

    cvt_bf16<<<dim3(4704), 256, 0, stream>>>(x, xb, 1204224);
    cvt_bf16<<<dim3(192),  256, 0, stream>>>(Wq, wb, 49152);
    cvt_bf16<<<dim3(384),  256, 0, stream>>>(Wkv, wb + 196608, 98304);
    cvt_bf16<<<dim3(192),  256, 0, stream>>>(Wo, wob, 49152);

    gemm_mfma<384, false><<<dim3(49, 12, 4), 256, 0, stream>>>(
        xb, wb, nullptr, qkvb, nullptr, QKV_CH);
    natt2<<<dim3(49, 8, 4), 256, 0, stream>>>(qkvb, aob);
    gemm_mfma<512, true><<<dim3(49, 3, 4), 256, 0, stream>>>(
        aob, wob, bo, nullptr, out, 384);
}

// Round 7
// 152.141 us; speedup vs baseline: 3.5293x; 1.0378x over previous
//
#include <hip/hip_runtime.h>

// ConvAttention2d: B=4, DIM=384, HEADS=8, DH=64, INNER=512, H=W=56, KS=3
// fp32 in/out. Internals: bf16 MFMA GEMMs (fp32 accum), bf16 qkv/ao buffers.
// qkv = x @ [Wq;Wkv] -> 3x3 neighborhood attention -> out = ao @ Wo + bo
// R7 = R6 resubmit (infra failure): x pre-transposed to blocked (s,k) tiles;
// gemm1 B-staging via global_load_lds (1 instr/wave/K-step vs 8 scalar loads).

#define HW 3136
#define WIMG 56
#define QKV_CH 1536
#define SCALE 0.125f
#define SLEN 200   // natt LDS row stride (ushorts)

typedef __bf16 bf16x8_t __attribute__((ext_vector_type(8)));
typedef float f32x4_t __attribute__((ext_vector_type(4)));

__device__ __forceinline__ float bf2f(unsigned short u) {
    return __uint_as_float(((unsigned int)u) << 16);
}
__device__ __forceinline__ unsigned short f2bf(float f) {
    unsigned int u = __float_as_uint(f);
    u += 0x7FFFu + ((u >> 16) & 1u);   // round-to-nearest-even
    return (unsigned short)(u >> 16);
}
// 16B-granule rotation (A-path LDS swizzle)
__device__ __forceinline__ int gpos(int g, int row) { return (g + ((row >> 1) & 3)) & 3; }

// ---------------------------------------------------------------------------
// All three weight matrices f32 -> bf16 in one launch. wdst = wb||wob
// contiguous: [Wq 49152 | Wkv 98304 | Wo 49152] uint4 slots (196608 total).
// ---------------------------------------------------------------------------
__global__ __launch_bounds__(256) void cvt_w_all(
    const float* __restrict__ Wq, const float* __restrict__ Wkv,
    const float* __restrict__ Wo, unsigned short* __restrict__ wdst)
{
    const int i = blockIdx.x * 256 + threadIdx.x;   // uint4 slot
    const float* src; int base;
    if (i < 49152)       { src = Wq;  base = 0; }
    else if (i < 147456) { src = Wkv; base = 49152; }
    else                 { src = Wo;  base = 147456; }
    const float4 v = reinterpret_cast<const float4*>(src)[i - base];
    uint2 u;
    u.x = (unsigned int)f2bf(v.x) | ((unsigned int)f2bf(v.y) << 16);
    u.y = (unsigned int)f2bf(v.z) | ((unsigned int)f2bf(v.w) << 16);
    reinterpret_cast<uint2*>(wdst)[i] = u;
}

// ---------------------------------------------------------------------------
// x (b,c,s) f32 -> blocked bf16 xT[b][sblk][kblk][64 s][32 k] (4KB tiles).
// LDS transpose keeps both sides coalesced. grid (49,12,4), block 256.
// ---------------------------------------------------------------------------
__global__ __launch_bounds__(256) void cvtT_x(
    const float* __restrict__ x, unsigned short* __restrict__ xT)
{
    __shared__ unsigned short Tl[64 * 36];   // [s][c], pad 36 (rows 8B-aligned)
    const int sblk = blockIdx.x, kblk = blockIdx.y, b = blockIdx.z;
    const int t = threadIdx.x;

    const float* xp = x + ((size_t)b * 384 + (size_t)kblk * 32) * HW + sblk * 64;
    const int c = t >> 3;                    // 0..31
#pragma unroll
    for (int i = 0; i < 2; i++) {
        const int sc = (t & 7) + 8 * i;      // 0..15 (float4 chunks)
        const float4 v = *reinterpret_cast<const float4*>(xp + (size_t)c * HW + sc * 4);
        const int s4 = sc * 4;
        Tl[(s4 + 0) * 36 + c] = f2bf(v.x);
        Tl[(s4 + 1) * 36 + c] = f2bf(v.y);
        Tl[(s4 + 2) * 36 + c] = f2bf(v.z);
        Tl[(s4 + 3) * 36 + c] = f2bf(v.w);
    }
    __syncthreads();

    const int row = t >> 2, gran = t & 3;    // [64][32] row-major out
    const uint2 lo = *reinterpret_cast<const uint2*>(&Tl[row * 36 + gran * 8]);
    const uint2 hi = *reinterpret_cast<const uint2*>(&Tl[row * 36 + gran * 8 + 4]);
    uint4 o; o.x = lo.x; o.y = lo.y; o.z = hi.x; o.w = hi.y;
    unsigned short* dst = xT + ((((size_t)b * 49 + sblk) * 12 + kblk) << 11); // *2048
    *reinterpret_cast<uint4*>(dst + t * 8) = o;
}

// ---------------------------------------------------------------------------
// GEMM1: qkv[b][o][s] = sum_c W[o][c] * x[c][s], via blocked xT.
// Tile 128o x 64s, K-step 32. B staged by global_load_lds (1KB/wave/step).
// grid (49, 12, 4), block 256.
// ---------------------------------------------------------------------------
__global__ __launch_bounds__(256) void gemm1(
    const unsigned short* __restrict__ xT,   // blocked (see cvtT_x)
    const unsigned short* __restrict__ Wb,   // (1536, 384) bf16
    unsigned short* __restrict__ qkv)        // (4,1536,3136) bf16
{
    __shared__ __align__(16) unsigned short A_lds[128 * 32];
    __shared__ __align__(16) unsigned short B_lds[64 * 32];

    const int sblk = blockIdx.x;
    const int o0 = blockIdx.y * 128;
    const int b  = blockIdx.z;
    const int t  = threadIdx.x;
    const int lane = t & 63, w = t >> 6;
    const int quad = lane >> 4, mrow = lane & 15;

    const int ar = t >> 2, ag = t & 3;
    const unsigned short* wr0 = Wb + (size_t)(o0 + ar) * 384;
    const unsigned short* wr1 = Wb + (size_t)(o0 + 64 + ar) * 384;
    const unsigned short* xsrc = xT + (((size_t)b * 49 + sblk) * 12 << 11)
                               + w * 512 + lane * 8;          // per-lane 16B

    f32x4_t acc[2][4];
#pragma unroll
    for (int m = 0; m < 2; m++)
#pragma unroll
        for (int nt = 0; nt < 4; nt++) acc[m][nt] = (f32x4_t){0.f, 0.f, 0.f, 0.f};

    for (int kb = 0; kb < 12; kb++) {
        const uint4 a0 = *reinterpret_cast<const uint4*>(wr0 + kb * 32 + ag * 8);
        const uint4 a1 = *reinterpret_cast<const uint4*>(wr1 + kb * 32 + ag * 8);

        __syncthreads();   // previous iteration's fragment reads done
        __builtin_amdgcn_global_load_lds(
            (const __attribute__((address_space(1))) unsigned int*)(xsrc + (size_t)kb * 2048),
            (__attribute__((address_space(3))) unsigned int*)(B_lds + w * 512),
            16, 0, 0);
        *reinterpret_cast<uint4*>(&A_lds[ar * 32 + gpos(ag, ar) * 8]) = a0;
        *reinterpret_cast<uint4*>(&A_lds[(64 + ar) * 32 + gpos(ag, 64 + ar) * 8]) = a1;
        __syncthreads();   // drains vmcnt (global_load_lds) + lgkm

        bf16x8_t bfr[4];
#pragma unroll
        for (int nt = 0; nt < 4; nt++)
            bfr[nt] = *reinterpret_cast<const bf16x8_t*>(&B_lds[(nt * 16 + mrow) * 32 + quad * 8]);
#pragma unroll
        for (int m = 0; m < 2; m++) {
            const int orow = w * 32 + m * 16 + mrow;
            const bf16x8_t af = *reinterpret_cast<const bf16x8_t*>(&A_lds[orow * 32 + gpos(quad, orow) * 8]);
#pragma unroll
            for (int nt = 0; nt < 4; nt++)
                acc[m][nt] = __builtin_amdgcn_mfma_f32_16x16x32_bf16(af, bfr[nt], acc[m][nt], 0, 0, 0);
        }
    }

    const int s0 = sblk * 64;
#pragma unroll
    for (int m = 0; m < 2; m++)
#pragma unroll
        for (int nt = 0; nt < 4; nt++)
#pragma unroll
            for (int r = 0; r < 4; r++) {
                const int oo = o0 + w * 32 + m * 16 + quad * 4 + r;
                const int ss = s0 + nt * 16 + mrow;
                qkv[(size_t)b * QKV_CH * HW + (size_t)oo * HW + ss] = f2bf(acc[m][nt][r]);
            }
}

// ---------------------------------------------------------------------------
// GEMM3: out[b][o][s] = sum_c Wo[o][c] * ao[b][c][s] + bo[o]
// Tile 128o x 64s, K=512. grid (49, 3, 4), block 256.
// ---------------------------------------------------------------------------
__global__ __launch_bounds__(256) void gemm3(
    const unsigned short* __restrict__ ao,   // (4,512,3136) bf16
    const unsigned short* __restrict__ Wb,   // (384,512) bf16
    const float* __restrict__ bias,          // (384)
    float* __restrict__ out)                 // (4,384,3136) f32
{
    __shared__ __align__(16) unsigned short A_lds[128 * 32];
    __shared__ __align__(16) unsigned short B_lds[64 * 32];

    const int s0 = blockIdx.x * 64;
    const int o0 = blockIdx.y * 128;
    const int b  = blockIdx.z;
    const int t  = threadIdx.x;
    const int lane = t & 63, w = t >> 6;
    const int quad = lane >> 4, mrow = lane & 15;

    const int ar = t >> 2, ag = t & 3;
    const int bs = t & 63, bg = t >> 6;

    const unsigned short* xp = ao + (size_t)b * 512 * HW + s0 + bs;
    const unsigned short* wr0 = Wb + (size_t)(o0 + ar) * 512;
    const unsigned short* wr1 = Wb + (size_t)(o0 + 64 + ar) * 512;

    f32x4_t acc[2][4];
#pragma unroll
    for (int m = 0; m < 2; m++)
#pragma unroll
        for (int nt = 0; nt < 4; nt++) acc[m][nt] = (f32x4_t){0.f, 0.f, 0.f, 0.f};

    for (int k0 = 0; k0 < 512; k0 += 32) {
        const uint4 a0 = *reinterpret_cast<const uint4*>(wr0 + k0 + ag * 8);
        const uint4 a1 = *reinterpret_cast<const uint4*>(wr1 + k0 + ag * 8);
        __align__(16) unsigned short bv[8];
#pragma unroll
        for (int j = 0; j < 8; j++)
            bv[j] = xp[(size_t)(k0 + bg * 8 + j) * HW];

        __syncthreads();
        *reinterpret_cast<uint4*>(&A_lds[ar * 32 + gpos(ag, ar) * 8]) = a0;
        *reinterpret_cast<uint4*>(&A_lds[(64 + ar) * 32 + gpos(ag, 64 + ar) * 8]) = a1;
        *reinterpret_cast<uint4*>(&B_lds[bs * 32 + gpos(bg, bs) * 8]) =
            *reinterpret_cast<const uint4*>(bv);
        __syncthreads();

        bf16x8_t bfr[4];
#pragma unroll
        for (int nt = 0; nt < 4; nt++) {
            const int srow = nt * 16 + mrow;
            bfr[nt] = *reinterpret_cast<const bf16x8_t*>(&B_lds[srow * 32 + gpos(quad, srow) * 8]);
        }
#pragma unroll
        for (int m = 0; m < 2; m++) {
            const int orow = w * 32 + m * 16 + mrow;
            const bf16x8_t af = *reinterpret_cast<const bf16x8_t*>(&A_lds[orow * 32 + gpos(quad, orow) * 8]);
#pragma unroll
            for (int nt = 0; nt < 4; nt++)
                acc[m][nt] = __builtin_amdgcn_mfma_f32_16x16x32_bf16(af, bfr[nt], acc[m][nt], 0, 0, 0);
        }
    }

#pragma unroll
    for (int m = 0; m < 2; m++)
#pragma unroll
        for (int nt = 0; nt < 4; nt++)
#pragma unroll
            for (int r = 0; r < 4; r++) {
                const int oo = o0 + w * 32 + m * 16 + quad * 4 + r;
                const int ss = s0 + nt * 16 + mrow;
                out[(size_t)b * 384 * HW + (size_t)oo * HW + ss] = acc[m][nt][r] + bias[oo];
            }
}

// ---------------------------------------------------------------------------
// Neighborhood attention v2: LDS halo staging (unchanged from R5).
// ---------------------------------------------------------------------------
__global__ __launch_bounds__(256) void natt2(
    const unsigned short* __restrict__ qkv,  // (4,1536,3136) bf16
    unsigned short* __restrict__ ao)         // (4,512,3136) bf16
{
    __shared__ __align__(16) unsigned short smem[2 * 64 * SLEN]; // Kl | Vl
    unsigned short* Kl = smem;
    unsigned short* Vl = smem + 64 * SLEN;
    float* dred = reinterpret_cast<float*>(smem);  // overlays Kl after dots

    const int t = threadIdx.x, lane = t & 63, w = t >> 6;
    const int s0 = blockIdx.x * 64;
    const int s  = s0 + lane;
    const int h  = blockIdx.y, b = blockIdx.z;
    const int y  = s / WIMG, xx = s % WIMG;

    const size_t hbase = (size_t)b * QKV_CH * HW + (size_t)(h * 64) * HW;
    const unsigned short* kg = qkv + hbase + (size_t)512 * HW;
    const unsigned short* vg = qkv + hbase + (size_t)1024 * HW;

#pragma unroll
    for (int i = 0; i < 6; i++) {
        const int f = i * 256 + t;        // 0..1535
        const int d = f / 24, j = f % 24;
        int g = s0 - 64 + j * 8;
        g = min(max(g, 0), HW - 8);       // clamped slots only read by masked taps
        const uint4 k4 = *reinterpret_cast<const uint4*>(kg + (size_t)d * HW + g);
        const uint4 v4 = *reinterpret_cast<const uint4*>(vg + (size_t)d * HW + g);
        *reinterpret_cast<uint4*>(&Kl[d * SLEN + j * 8]) = k4;
        *reinterpret_cast<uint4*>(&Vl[d * SLEN + j * 8]) = v4;
    }

    int   off9[9];
    float msk[9];
#pragma unroll
    for (int ty = 0; ty < 3; ty++)
#pragma unroll
        for (int tx = 0; tx < 3; tx++) {
            const int tap = ty * 3 + tx;
            const int ny = y + ty - 1, nx = xx + tx - 1;
            const bool v = (ny >= 0) && (ny < WIMG) && (nx >= 0) && (nx < WIMG);
            off9[tap] = v ? ((ty - 1) * WIMG + (tx - 1)) : 0;
            msk[tap]  = v ? 1.f : 0.f;
        }

    __syncthreads();

    const unsigned short* qp = qkv + hbase + s;
    float dots[9];
#pragma unroll
    for (int tp = 0; tp < 9; tp++) dots[tp] = 0.f;
#pragma unroll 4
    for (int dd = 0; dd < 16; dd++) {
        const int d = w * 16 + dd;
        const float qv = bf2f(qp[(size_t)d * HW]);
        const int bi = d * SLEN + lane + 64;
#pragma unroll
        for (int tp = 0; tp < 9; tp++)
            dots[tp] += qv * bf2f(Kl[bi + off9[tp]]);
    }

    __syncthreads();
#pragma unroll
    for (int tp = 0; tp < 9; tp++) dred[(tp * 4 + w) * 64 + lane] = dots[tp];
    __syncthreads();

    float mx = -1e30f, dt[9];
#pragma unroll
    for (int tp = 0; tp < 9; tp++) {
        const float sum = dred[(tp * 4 + 0) * 64 + lane] + dred[(tp * 4 + 1) * 64 + lane] +
                          dred[(tp * 4 + 2) * 64 + lane] + dred[(tp * 4 + 3) * 64 + lane];
        dt[tp] = msk[tp] * (sum * SCALE);
        mx = fmaxf(mx, dt[tp]);
    }
    float se = 0.f, w9[9];
#pragma unroll
    for (int tp = 0; tp < 9; tp++) { w9[tp] = __expf(dt[tp] - mx); se += w9[tp]; }
    const float inv = 1.f / se;
#pragma unroll
    for (int tp = 0; tp < 9; tp++) w9[tp] *= inv * msk[tp];

    unsigned short* aop = ao + (size_t)b * 512 * HW + (size_t)(h * 64) * HW + s;
#pragma unroll 4
    for (int dd = 0; dd < 16; dd++) {
        const int d = w * 16 + dd;
        const int bi = d * SLEN + lane + 64;
        float o = 0.f;
#pragma unroll
        for (int tp = 0; tp < 9; tp++)
            o += w9[tp] * bf2f(Vl[bi + off9[tp]]);
        aop[(size_t)d * HW] = f2bf(o);
    }
}

extern "C" void kernel_launch(void* const* d_in, const int* in_sizes, int n_in,
                              void* d_out, int out_size, void* d_ws, size_t ws_size,
                              hipStream_t stream) {
    const float* x   = (const float*)d_in[0];
    const float* Wq  = (const float*)d_in[1];
    const float* Wkv = (const float*)d_in[2];
    const float* Wo  = (const float*)d_in[3];
    const float* bo  = (const float*)d_in[4];
    float* out = (float*)d_out;

    // ws layout (bf16 elements)
    unsigned short* xT   = (unsigned short*)d_ws;                 // 4*49*12*2048 = 4,816,896
    unsigned short* wb   = xT + (size_t)4 * 384 * HW;             // 1536*384     =   589,824
    unsigned short* wob  = wb + (size_t)1536 * 384;               // 384*512      =   196,608
    unsigned short* qkvb = wob + (size_t)384 * 512;               // 4*1536*3136  = 19,267,584
    unsigned short* aob  = qkvb + (size_t)4 * QKV_CH * HW;        // 4*512*3136   =  6,422,528

    cvt_w_all<<<dim3(768), 256, 0, stream>>>(Wq, Wkv, Wo, wb);
    cvtT_x<<<dim3(49, 12, 4), 256, 0, stream>>>(x, xT);

    gemm1<<<dim3(49, 12, 4), 256, 0, stream>>>(xT, wb, qkvb);
    natt2<<<dim3(49, 8, 4), 256, 0, stream>>>(qkvb, aob);
    gemm3<<<dim3(49, 3, 4), 256, 0, stream>>>(aob, wob, bo, out);
}

// Round 10
// 149.546 us; speedup vs baseline: 3.5905x; 1.0174x over previous
//
#include <hip/hip_runtime.h>

// ConvAttention2d: B=4, DIM=384, HEADS=8, DH=64, INNER=512, H=W=56, KS=3
// fp32 in/out. Internals: bf16 MFMA GEMMs (fp32 accum), bf16 qkv/ao buffers.
// qkv = x @ [Wq;Wkv] -> 3x3 neighborhood attention -> out = ao @ Wo + bo
// R10: gemm1 keeps the 128x128 tile (16 MFMA/wave/K-step) but stages via
// explicit global_load_dwordx4 + ds_write_b128 (the multi-issue
// global_load_lds pattern of R8/R9 is the only never-passing machinery;
// both container failures implicate it).

#define HW 3136
#define WIMG 56
#define QKV_CH 1536
#define SCALE 0.125f
#define SLEN 200   // natt LDS row stride (ushorts)

typedef __bf16 bf16x8_t __attribute__((ext_vector_type(8)));
typedef float f32x4_t __attribute__((ext_vector_type(4)));

__device__ __forceinline__ float bf2f(unsigned short u) {
    return __uint_as_float(((unsigned int)u) << 16);
}
__device__ __forceinline__ unsigned short f2bf(float f) {
    unsigned int u = __float_as_uint(f);
    u += 0x7FFFu + ((u >> 16) & 1u);   // round-to-nearest-even
    return (unsigned short)(u >> 16);
}
// 16B-granule rotation (used by gemm3's VALU-staged LDS)
__device__ __forceinline__ int gpos(int g, int row) { return (g + ((row >> 1) & 3)) & 3; }

// ---------------------------------------------------------------------------
// Weights f32 -> bf16. qkv weights -> blocked wT[oblk12][kb12][128o][32k]
// (pure re-tiling: 16B k-granules stay contiguous). Wo -> flat wob.
// Thread = one uint4 (8 source floats). 73728 + 24576 = 98304 threads =
// exactly 384 blocks.
// ---------------------------------------------------------------------------
__global__ __launch_bounds__(256) void cvt_w(
    const float* __restrict__ Wq, const float* __restrict__ Wkv,
    const float* __restrict__ Wo,
    unsigned short* __restrict__ wT, unsigned short* __restrict__ wob)
{
    const int i = blockIdx.x * 256 + threadIdx.x;
    if (i < 73728) {                    // wT: 12*12*128*4 uint4 slots
        const int g = i & 3;
        const int idx3 = i >> 2;        // [oblk][kb][o128]
        const int o128 = idx3 & 127;
        const int rest = idx3 >> 7;     // 0..143
        const int kb = rest % 12, oblk = rest / 12;
        const int o = oblk * 128 + o128;
        const int k0 = kb * 32 + g * 8;
        const float* src = (o < 512) ? (Wq + (size_t)o * 384 + k0)
                                     : (Wkv + (size_t)(o - 512) * 384 + k0);
        const float4 v0 = *reinterpret_cast<const float4*>(src);
        const float4 v1 = *reinterpret_cast<const float4*>(src + 4);
        uint4 u;
        u.x = (unsigned int)f2bf(v0.x) | ((unsigned int)f2bf(v0.y) << 16);
        u.y = (unsigned int)f2bf(v0.z) | ((unsigned int)f2bf(v0.w) << 16);
        u.z = (unsigned int)f2bf(v1.x) | ((unsigned int)f2bf(v1.y) << 16);
        u.w = (unsigned int)f2bf(v1.z) | ((unsigned int)f2bf(v1.w) << 16);
        reinterpret_cast<uint4*>(wT)[i] = u;
    } else {                            // wob: 24576 uint4 slots
        const int j = i - 73728;        // grid sized exactly -> j in [0,24576)
        const float4 v0 = reinterpret_cast<const float4*>(Wo)[j * 2];
        const float4 v1 = reinterpret_cast<const float4*>(Wo)[j * 2 + 1];
        uint4 u;
        u.x = (unsigned int)f2bf(v0.x) | ((unsigned int)f2bf(v0.y) << 16);
        u.y = (unsigned int)f2bf(v0.z) | ((unsigned int)f2bf(v0.w) << 16);
        u.z = (unsigned int)f2bf(v1.x) | ((unsigned int)f2bf(v1.y) << 16);
        u.w = (unsigned int)f2bf(v1.z) | ((unsigned int)f2bf(v1.w) << 16);
        reinterpret_cast<uint4*>(wob)[j] = u;
    }
}

// ---------------------------------------------------------------------------
// x (b,c,s) f32 -> blocked bf16 xT[b][sblk25][kb12][128s][32k], s padded to
// 3200 (tail zero-filled). grid (50,12,4): blockIdx.x==49 zero-fills the
// padded half-tile of s-tile 24; else LDS-transpose of a 64s x 32k slab.
// ---------------------------------------------------------------------------
__global__ __launch_bounds__(256) void cvtT_x(
    const float* __restrict__ x, unsigned short* __restrict__ xT)
{
    __shared__ unsigned short Tl[64 * 36];   // [s][c], pad 36
    const int sblk = blockIdx.x, kblk = blockIdx.y, b = blockIdx.z;
    const int t = threadIdx.x;

    if (sblk == 49) {                   // zero-fill s in [3136,3200)
        unsigned short* dst = xT + (((size_t)b * 25 + 24) * 12 + kblk) * 4096 + 2048;
        *reinterpret_cast<uint4*>(dst + t * 8) = (uint4){0, 0, 0, 0};
        return;
    }

    const float* xp = x + ((size_t)b * 384 + (size_t)kblk * 32) * HW + sblk * 64;
    const int c = t >> 3;                    // 0..31
#pragma unroll
    for (int i = 0; i < 2; i++) {
        const int sc = (t & 7) + 8 * i;      // 0..15 (float4 chunks)
        const float4 v = *reinterpret_cast<const float4*>(xp + (size_t)c * HW + sc * 4);
        const int s4 = sc * 4;
        Tl[(s4 + 0) * 36 + c] = f2bf(v.x);
        Tl[(s4 + 1) * 36 + c] = f2bf(v.y);
        Tl[(s4 + 2) * 36 + c] = f2bf(v.z);
        Tl[(s4 + 3) * 36 + c] = f2bf(v.w);
    }
    __syncthreads();

    const int row = t >> 2, gran = t & 3;
    const uint2 lo = *reinterpret_cast<const uint2*>(&Tl[row * 36 + gran * 8]);
    const uint2 hi = *reinterpret_cast<const uint2*>(&Tl[row * 36 + gran * 8 + 4]);
    uint4 o; o.x = lo.x; o.y = lo.y; o.z = hi.x; o.w = hi.y;
    unsigned short* dst = xT + (((size_t)b * 25 + (sblk >> 1)) * 12 + kblk) * 4096
                        + (sblk & 1) * 2048;
    *reinterpret_cast<uint4*>(dst + t * 8) = o;
}

// ---------------------------------------------------------------------------
// GEMM1: qkv[b][o][s] = sum_c W[o][c] * x[c][s]. Tile 128o x 128s, BK=32,
// 4 waves each owning a 64x64 quadrant (4x4 16x16 subtiles). A (wT) and B
// (xT) staged via explicit uint4 loads + ds_write_b128 (identity copy of
// the blocked 8KB tiles). grid (25, 12, 4). s >= 3136 guarded at store.
// ---------------------------------------------------------------------------
__global__ __launch_bounds__(256) void gemm1(
    const unsigned short* __restrict__ xT,   // [b][25][12][128][32]
    const unsigned short* __restrict__ wT,   // [12][12][128][32]
    unsigned short* __restrict__ qkv)        // (4,1536,3136) bf16
{
    __shared__ __align__(16) unsigned short A_lds[128 * 32];
    __shared__ __align__(16) unsigned short B_lds[128 * 32];

    const int sblk = blockIdx.x;             // 0..24
    const int oblk = blockIdx.y;             // 0..11
    const int b  = blockIdx.z;
    const int t  = threadIdx.x;
    const int lane = t & 63, w = t >> 6;
    const int quad = lane >> 4, mrow = lane & 15;
    const int wm = w >> 1, wn = w & 1;       // wave quadrant

    const unsigned short* wsrc = wT + ((size_t)oblk * 12) * 4096;
    const unsigned short* xsrc = xT + (((size_t)b * 25 + sblk) * 12) * 4096;

    f32x4_t acc[4][4];
#pragma unroll
    for (int m = 0; m < 4; m++)
#pragma unroll
        for (int n = 0; n < 4; n++) acc[m][n] = (f32x4_t){0.f, 0.f, 0.f, 0.f};

    for (int kb = 0; kb < 12; kb++) {
        // Coalesced identity copy: 8KB per operand, 2 uint4 per thread each.
        const uint4 a0 = *reinterpret_cast<const uint4*>(wsrc + (size_t)kb * 4096 + t * 8);
        const uint4 a1 = *reinterpret_cast<const uint4*>(wsrc + (size_t)kb * 4096 + 2048 + t * 8);
        const uint4 b0 = *reinterpret_cast<const uint4*>(xsrc + (size_t)kb * 4096 + t * 8);
        const uint4 b1 = *reinterpret_cast<const uint4*>(xsrc + (size_t)kb * 4096 + 2048 + t * 8);

        __syncthreads();   // previous iteration's fragment reads complete
        *reinterpret_cast<uint4*>(A_lds + t * 8) = a0;
        *reinterpret_cast<uint4*>(A_lds + 2048 + t * 8) = a1;
        *reinterpret_cast<uint4*>(B_lds + t * 8) = b0;
        *reinterpret_cast<uint4*>(B_lds + 2048 + t * 8) = b1;
        __syncthreads();

        bf16x8_t af[4], bf[4];
#pragma unroll
        for (int m = 0; m < 4; m++)
            af[m] = *reinterpret_cast<const bf16x8_t*>(&A_lds[(wm * 64 + m * 16 + mrow) * 32 + quad * 8]);
#pragma unroll
        for (int n = 0; n < 4; n++)
            bf[n] = *reinterpret_cast<const bf16x8_t*>(&B_lds[(wn * 64 + n * 16 + mrow) * 32 + quad * 8]);
#pragma unroll
        for (int m = 0; m < 4; m++)
#pragma unroll
            for (int n = 0; n < 4; n++)
                acc[m][n] = __builtin_amdgcn_mfma_f32_16x16x32_bf16(af[m], bf[n], acc[m][n], 0, 0, 0);
    }

    const int o0 = oblk * 128 + wm * 64;
    const int s0 = sblk * 128 + wn * 64;
    unsigned short* outb = qkv + (size_t)b * QKV_CH * HW;
#pragma unroll
    for (int m = 0; m < 4; m++)
#pragma unroll
        for (int n = 0; n < 4; n++) {
            const int ss = s0 + n * 16 + mrow;
            if (ss < HW) {
#pragma unroll
                for (int r = 0; r < 4; r++) {
                    const int oo = o0 + m * 16 + quad * 4 + r;
                    outb[(size_t)oo * HW + ss] = f2bf(acc[m][n][r]);
                }
            }
        }
}

// ---------------------------------------------------------------------------
// GEMM3: out[b][o][s] = sum_c Wo[o][c] * ao[b][c][s] + bo[o]  (unchanged R7)
// ---------------------------------------------------------------------------
__global__ __launch_bounds__(256) void gemm3(
    const unsigned short* __restrict__ ao,   // (4,512,3136) bf16
    const unsigned short* __restrict__ Wb,   // (384,512) bf16
    const float* __restrict__ bias,          // (384)
    float* __restrict__ out)                 // (4,384,3136) f32
{
    __shared__ __align__(16) unsigned short A_lds[128 * 32];
    __shared__ __align__(16) unsigned short B_lds[64 * 32];

    const int s0 = blockIdx.x * 64;
    const int o0 = blockIdx.y * 128;
    const int b  = blockIdx.z;
    const int t  = threadIdx.x;
    const int lane = t & 63, w = t >> 6;
    const int quad = lane >> 4, mrow = lane & 15;

    const int ar = t >> 2, ag = t & 3;
    const int bs = t & 63, bg = t >> 6;

    const unsigned short* xp = ao + (size_t)b * 512 * HW + s0 + bs;
    const unsigned short* wr0 = Wb + (size_t)(o0 + ar) * 512;
    const unsigned short* wr1 = Wb + (size_t)(o0 + 64 + ar) * 512;

    f32x4_t acc[2][4];
#pragma unroll
    for (int m = 0; m < 2; m++)
#pragma unroll
        for (int nt = 0; nt < 4; nt++) acc[m][nt] = (f32x4_t){0.f, 0.f, 0.f, 0.f};

    for (int k0 = 0; k0 < 512; k0 += 32) {
        const uint4 a0 = *reinterpret_cast<const uint4*>(wr0 + k0 + ag * 8);
        const uint4 a1 = *reinterpret_cast<const uint4*>(wr1 + k0 + ag * 8);
        __align__(16) unsigned short bv[8];
#pragma unroll
        for (int j = 0; j < 8; j++)
            bv[j] = xp[(size_t)(k0 + bg * 8 + j) * HW];

        __syncthreads();
        *reinterpret_cast<uint4*>(&A_lds[ar * 32 + gpos(ag, ar) * 8]) = a0;
        *reinterpret_cast<uint4*>(&A_lds[(64 + ar) * 32 + gpos(ag, 64 + ar) * 8]) = a1;
        *reinterpret_cast<uint4*>(&B_lds[bs * 32 + gpos(bg, bs) * 8]) =
            *reinterpret_cast<const uint4*>(bv);
        __syncthreads();

        bf16x8_t bfr[4];
#pragma unroll
        for (int nt = 0; nt < 4; nt++) {
            const int srow = nt * 16 + mrow;
            bfr[nt] = *reinterpret_cast<const bf16x8_t*>(&B_lds[srow * 32 + gpos(quad, srow) * 8]);
        }
#pragma unroll
        for (int m = 0; m < 2; m++) {
            const int orow = w * 32 + m * 16 + mrow;
            const bf16x8_t af = *reinterpret_cast<const bf16x8_t*>(&A_lds[orow * 32 + gpos(quad, orow) * 8]);
#pragma unroll
            for (int nt = 0; nt < 4; nt++)
                acc[m][nt] = __builtin_amdgcn_mfma_f32_16x16x32_bf16(af, bfr[nt], acc[m][nt], 0, 0, 0);
        }
    }

#pragma unroll
    for (int m = 0; m < 2; m++)
#pragma unroll
        for (int nt = 0; nt < 4; nt++)
#pragma unroll
            for (int r = 0; r < 4; r++) {
                const int oo = o0 + w * 32 + m * 16 + quad * 4 + r;
                const int ss = s0 + nt * 16 + mrow;
                out[(size_t)b * 384 * HW + (size_t)oo * HW + ss] = acc[m][nt][r] + bias[oo];
            }
}

// ---------------------------------------------------------------------------
// Neighborhood attention v2: LDS halo staging (unchanged R7).
// ---------------------------------------------------------------------------
__global__ __launch_bounds__(256) void natt2(
    const unsigned short* __restrict__ qkv,  // (4,1536,3136) bf16
    unsigned short* __restrict__ ao)         // (4,512,3136) bf16
{
    __shared__ __align__(16) unsigned short smem[2 * 64 * SLEN]; // Kl | Vl
    unsigned short* Kl = smem;
    unsigned short* Vl = smem + 64 * SLEN;
    float* dred = reinterpret_cast<float*>(smem);  // overlays Kl after dots

    const int t = threadIdx.x, lane = t & 63, w = t >> 6;
    const int s0 = blockIdx.x * 64;
    const int s  = s0 + lane;
    const int h  = blockIdx.y, b = blockIdx.z;
    const int y  = s / WIMG, xx = s % WIMG;

    const size_t hbase = (size_t)b * QKV_CH * HW + (size_t)(h * 64) * HW;
    const unsigned short* kg = qkv + hbase + (size_t)512 * HW;
    const unsigned short* vg = qkv + hbase + (size_t)1024 * HW;

#pragma unroll
    for (int i = 0; i < 6; i++) {
        const int f = i * 256 + t;        // 0..1535
        const int d = f / 24, j = f % 24;
        int g = s0 - 64 + j * 8;
        g = min(max(g, 0), HW - 8);       // clamped slots only read by masked taps
        const uint4 k4 = *reinterpret_cast<const uint4*>(kg + (size_t)d * HW + g);
        const uint4 v4 = *reinterpret_cast<const uint4*>(vg + (size_t)d * HW + g);
        *reinterpret_cast<uint4*>(&Kl[d * SLEN + j * 8]) = k4;
        *reinterpret_cast<uint4*>(&Vl[d * SLEN + j * 8]) = v4;
    }

    int   off9[9];
    float msk[9];
#pragma unroll
    for (int ty = 0; ty < 3; ty++)
#pragma unroll
        for (int tx = 0; tx < 3; tx++) {
            const int tap = ty * 3 + tx;
            const int ny = y + ty - 1, nx = xx + tx - 1;
            const bool v = (ny >= 0) && (ny < WIMG) && (nx >= 0) && (nx < WIMG);
            off9[tap] = v ? ((ty - 1) * WIMG + (tx - 1)) : 0;
            msk[tap]  = v ? 1.f : 0.f;
        }

    __syncthreads();

    const unsigned short* qp = qkv + hbase + s;
    float dots[9];
#pragma unroll
    for (int tp = 0; tp < 9; tp++) dots[tp] = 0.f;
#pragma unroll 4
    for (int dd = 0; dd < 16; dd++) {
        const int d = w * 16 + dd;
        const float qv = bf2f(qp[(size_t)d * HW]);
        const int bi = d * SLEN + lane + 64;
#pragma unroll
        for (int tp = 0; tp < 9; tp++)
            dots[tp] += qv * bf2f(Kl[bi + off9[tp]]);
    }

    __syncthreads();
#pragma unroll
    for (int tp = 0; tp < 9; tp++) dred[(tp * 4 + w) * 64 + lane] = dots[tp];
    __syncthreads();

    float mx = -1e30f, dt[9];
#pragma unroll
    for (int tp = 0; tp < 9; tp++) {
        const float sum = dred[(tp * 4 + 0) * 64 + lane] + dred[(tp * 4 + 1) * 64 + lane] +
                          dred[(tp * 4 + 2) * 64 + lane] + dred[(tp * 4 + 3) * 64 + lane];
        dt[tp] = msk[tp] * (sum * SCALE);
        mx = fmaxf(mx, dt[tp]);
    }
    float se = 0.f, w9[9];
#pragma unroll
    for (int tp = 0; tp < 9; tp++) { w9[tp] = __expf(dt[tp] - mx); se += w9[tp]; }
    const float inv = 1.f / se;
#pragma unroll
    for (int tp = 0; tp < 9; tp++) w9[tp] *= inv * msk[tp];

    unsigned short* aop = ao + (size_t)b * 512 * HW + (size_t)(h * 64) * HW + s;
#pragma unroll 4
    for (int dd = 0; dd < 16; dd++) {
        const int d = w * 16 + dd;
        const int bi = d * SLEN + lane + 64;
        float o = 0.f;
#pragma unroll
        for (int tp = 0; tp < 9; tp++)
            o += w9[tp] * bf2f(Vl[bi + off9[tp]]);
        aop[(size_t)d * HW] = f2bf(o);
    }
}

extern "C" void kernel_launch(void* const* d_in, const int* in_sizes, int n_in,
                              void* d_out, int out_size, void* d_ws, size_t ws_size,
                              hipStream_t stream) {
    const float* x   = (const float*)d_in[0];
    const float* Wq  = (const float*)d_in[1];
    const float* Wkv = (const float*)d_in[2];
    const float* Wo  = (const float*)d_in[3];
    const float* bo  = (const float*)d_in[4];
    float* out = (float*)d_out;

    // ws layout (bf16 elements)
    unsigned short* xT   = (unsigned short*)d_ws;                 // 4*25*12*4096 = 4,915,200
    unsigned short* wT   = xT + (size_t)4915200;                  // 12*12*128*32 =   589,824
    unsigned short* wob  = wT + (size_t)589824;                   // 384*512      =   196,608
    unsigned short* qkvb = wob + (size_t)196608;                  // 4*1536*3136  = 19,267,584
    unsigned short* aob  = qkvb + (size_t)4 * QKV_CH * HW;        // 4*512*3136   =  6,422,528

    cvt_w<<<dim3(384), 256, 0, stream>>>(Wq, Wkv, Wo, wT, wob);   // exact: 98304 threads
    cvtT_x<<<dim3(50, 12, 4), 256, 0, stream>>>(x, xT);

    gemm1<<<dim3(25, 12, 4), 256, 0, stream>>>(xT, wT, qkvb);
    natt2<<<dim3(49, 8, 4), 256, 0, stream>>>(qkvb, aob);
    gemm3<<<dim3(49, 3, 4), 256, 0, stream>>>(aob, wob, bo, out);
}

// Round 11
// 145.460 us; speedup vs baseline: 3.6914x; 1.0281x over previous
//
#include <hip/hip_runtime.h>

// ConvAttention2d: B=4, DIM=384, HEADS=8, DH=64, INNER=512, H=W=56, KS=3
// fp32 in/out. Internals: bf16 MFMA GEMMs (fp32 accum), blocked bf16 buffers.
// qkv = x @ [Wq;Wkv] -> 3x3 neighborhood attention -> out = ao @ Wo + bo
// R11: gemm3 path blocked end-to-end: natt2 writes blocked aoT (2 uint4
// stores/thread), Wo pre-blocked, gemm3 = identity-staged MFMA clone of
// gemm1. gemm1/cvtT_x unchanged from R10.

#define HW 3136
#define WIMG 56
#define QKV_CH 1536
#define SCALE 0.125f
#define SLEN 200   // natt LDS row stride (ushorts)

typedef __bf16 bf16x8_t __attribute__((ext_vector_type(8)));
typedef float f32x4_t __attribute__((ext_vector_type(4)));

__device__ __forceinline__ float bf2f(unsigned short u) {
    return __uint_as_float(((unsigned int)u) << 16);
}
__device__ __forceinline__ unsigned short f2bf(float f) {
    unsigned int u = __float_as_uint(f);
    u += 0x7FFFu + ((u >> 16) & 1u);   // round-to-nearest-even
    return (unsigned short)(u >> 16);
}

// ---------------------------------------------------------------------------
// Weights f32 -> bf16, both blocked:
//   wT  [oblk12][kb12][128o][32k]  for gemm1 (Wq||Wkv, K=384)
//   wT3 [oblk3][kb16][128o][32k]   for gemm3 (Wo, K=512)
// Thread = one uint4 (8 source floats). 73728 + 24576 = 98304 = 384 blocks.
// ---------------------------------------------------------------------------
__global__ __launch_bounds__(256) void cvt_w(
    const float* __restrict__ Wq, const float* __restrict__ Wkv,
    const float* __restrict__ Wo,
    unsigned short* __restrict__ wT, unsigned short* __restrict__ wT3)
{
    const int i = blockIdx.x * 256 + threadIdx.x;
    if (i < 73728) {                    // wT: 12*12*128*4 uint4 slots
        const int g = i & 3;
        const int idx3 = i >> 2;        // [oblk][kb][o128]
        const int o128 = idx3 & 127;
        const int rest = idx3 >> 7;     // 0..143
        const int kb = rest % 12, oblk = rest / 12;
        const int o = oblk * 128 + o128;
        const int k0 = kb * 32 + g * 8;
        const float* src = (o < 512) ? (Wq + (size_t)o * 384 + k0)
                                     : (Wkv + (size_t)(o - 512) * 384 + k0);
        const float4 v0 = *reinterpret_cast<const float4*>(src);
        const float4 v1 = *reinterpret_cast<const float4*>(src + 4);
        uint4 u;
        u.x = (unsigned int)f2bf(v0.x) | ((unsigned int)f2bf(v0.y) << 16);
        u.y = (unsigned int)f2bf(v0.z) | ((unsigned int)f2bf(v0.w) << 16);
        u.z = (unsigned int)f2bf(v1.x) | ((unsigned int)f2bf(v1.y) << 16);
        u.w = (unsigned int)f2bf(v1.z) | ((unsigned int)f2bf(v1.w) << 16);
        reinterpret_cast<uint4*>(wT)[i] = u;
    } else {                            // wT3: 3*16*128*4 = 24576 uint4 slots
        const int j = i - 73728;        // [0, 24576)
        const int g = j & 3;
        const int idx3 = j >> 2;        // 0..6143
        const int o128 = idx3 & 127;
        const int rest = idx3 >> 7;     // 0..47
        const int kb = rest % 16, oblk = rest / 16;
        const int o = oblk * 128 + o128;            // < 384
        const float* src = Wo + (size_t)o * 512 + kb * 32 + g * 8;
        const float4 v0 = *reinterpret_cast<const float4*>(src);
        const float4 v1 = *reinterpret_cast<const float4*>(src + 4);
        uint4 u;
        u.x = (unsigned int)f2bf(v0.x) | ((unsigned int)f2bf(v0.y) << 16);
        u.y = (unsigned int)f2bf(v0.z) | ((unsigned int)f2bf(v0.w) << 16);
        u.z = (unsigned int)f2bf(v1.x) | ((unsigned int)f2bf(v1.y) << 16);
        u.w = (unsigned int)f2bf(v1.z) | ((unsigned int)f2bf(v1.w) << 16);
        reinterpret_cast<uint4*>(wT3)[j] = u;
    }
}

// ---------------------------------------------------------------------------
// x (b,c,s) f32 -> blocked bf16 xT[b][sblk25][kb12][128s][32k], s padded to
// 3200 (tail zero-filled). Unchanged from R10.
// ---------------------------------------------------------------------------
__global__ __launch_bounds__(256) void cvtT_x(
    const float* __restrict__ x, unsigned short* __restrict__ xT)
{
    __shared__ unsigned short Tl[64 * 36];   // [s][c], pad 36
    const int sblk = blockIdx.x, kblk = blockIdx.y, b = blockIdx.z;
    const int t = threadIdx.x;

    if (sblk == 49) {                   // zero-fill s in [3136,3200)
        unsigned short* dst = xT + (((size_t)b * 25 + 24) * 12 + kblk) * 4096 + 2048;
        *reinterpret_cast<uint4*>(dst + t * 8) = (uint4){0, 0, 0, 0};
        return;
    }

    const float* xp = x + ((size_t)b * 384 + (size_t)kblk * 32) * HW + sblk * 64;
    const int c = t >> 3;                    // 0..31
#pragma unroll
    for (int i = 0; i < 2; i++) {
        const int sc = (t & 7) + 8 * i;      // 0..15 (float4 chunks)
        const float4 v = *reinterpret_cast<const float4*>(xp + (size_t)c * HW + sc * 4);
        const int s4 = sc * 4;
        Tl[(s4 + 0) * 36 + c] = f2bf(v.x);
        Tl[(s4 + 1) * 36 + c] = f2bf(v.y);
        Tl[(s4 + 2) * 36 + c] = f2bf(v.z);
        Tl[(s4 + 3) * 36 + c] = f2bf(v.w);
    }
    __syncthreads();

    const int row = t >> 2, gran = t & 3;
    const uint2 lo = *reinterpret_cast<const uint2*>(&Tl[row * 36 + gran * 8]);
    const uint2 hi = *reinterpret_cast<const uint2*>(&Tl[row * 36 + gran * 8 + 4]);
    uint4 o; o.x = lo.x; o.y = lo.y; o.z = hi.x; o.w = hi.y;
    unsigned short* dst = xT + (((size_t)b * 25 + (sblk >> 1)) * 12 + kblk) * 4096
                        + (sblk & 1) * 2048;
    *reinterpret_cast<uint4*>(dst + t * 8) = o;
}

// ---------------------------------------------------------------------------
// GEMM1: unchanged from R10 (passing). Tile 128o x 128s, BK=32, identity
// uint4 staging, 16 MFMA/wave/K-step. grid (25, 12, 4).
// ---------------------------------------------------------------------------
__global__ __launch_bounds__(256) void gemm1(
    const unsigned short* __restrict__ xT,   // [b][25][12][128][32]
    const unsigned short* __restrict__ wT,   // [12][12][128][32]
    unsigned short* __restrict__ qkv)        // (4,1536,3136) bf16
{
    __shared__ __align__(16) unsigned short A_lds[128 * 32];
    __shared__ __align__(16) unsigned short B_lds[128 * 32];

    const int sblk = blockIdx.x;             // 0..24
    const int oblk = blockIdx.y;             // 0..11
    const int b  = blockIdx.z;
    const int t  = threadIdx.x;
    const int lane = t & 63, w = t >> 6;
    const int quad = lane >> 4, mrow = lane & 15;
    const int wm = w >> 1, wn = w & 1;       // wave quadrant

    const unsigned short* wsrc = wT + ((size_t)oblk * 12) * 4096;
    const unsigned short* xsrc = xT + (((size_t)b * 25 + sblk) * 12) * 4096;

    f32x4_t acc[4][4];
#pragma unroll
    for (int m = 0; m < 4; m++)
#pragma unroll
        for (int n = 0; n < 4; n++) acc[m][n] = (f32x4_t){0.f, 0.f, 0.f, 0.f};

    for (int kb = 0; kb < 12; kb++) {
        const uint4 a0 = *reinterpret_cast<const uint4*>(wsrc + (size_t)kb * 4096 + t * 8);
        const uint4 a1 = *reinterpret_cast<const uint4*>(wsrc + (size_t)kb * 4096 + 2048 + t * 8);
        const uint4 b0 = *reinterpret_cast<const uint4*>(xsrc + (size_t)kb * 4096 + t * 8);
        const uint4 b1 = *reinterpret_cast<const uint4*>(xsrc + (size_t)kb * 4096 + 2048 + t * 8);

        __syncthreads();   // previous iteration's fragment reads complete
        *reinterpret_cast<uint4*>(A_lds + t * 8) = a0;
        *reinterpret_cast<uint4*>(A_lds + 2048 + t * 8) = a1;
        *reinterpret_cast<uint4*>(B_lds + t * 8) = b0;
        *reinterpret_cast<uint4*>(B_lds + 2048 + t * 8) = b1;
        __syncthreads();

        bf16x8_t af[4], bf[4];
#pragma unroll
        for (int m = 0; m < 4; m++)
            af[m] = *reinterpret_cast<const bf16x8_t*>(&A_lds[(wm * 64 + m * 16 + mrow) * 32 + quad * 8]);
#pragma unroll
        for (int n = 0; n < 4; n++)
            bf[n] = *reinterpret_cast<const bf16x8_t*>(&B_lds[(wn * 64 + n * 16 + mrow) * 32 + quad * 8]);
#pragma unroll
        for (int m = 0; m < 4; m++)
#pragma unroll
            for (int n = 0; n < 4; n++)
                acc[m][n] = __builtin_amdgcn_mfma_f32_16x16x32_bf16(af[m], bf[n], acc[m][n], 0, 0, 0);
    }

    const int o0 = oblk * 128 + wm * 64;
    const int s0 = sblk * 128 + wn * 64;
    unsigned short* outb = qkv + (size_t)b * QKV_CH * HW;
#pragma unroll
    for (int m = 0; m < 4; m++)
#pragma unroll
        for (int n = 0; n < 4; n++) {
            const int ss = s0 + n * 16 + mrow;
            if (ss < HW) {
#pragma unroll
                for (int r = 0; r < 4; r++) {
                    const int oo = o0 + m * 16 + quad * 4 + r;
                    outb[(size_t)oo * HW + ss] = f2bf(acc[m][n][r]);
                }
            }
        }
}

// ---------------------------------------------------------------------------
// Neighborhood attention v3: R7 compute, blocked aoT output.
// aoT[b][sblk49][kb16][64s][32k]; thread (w,lane)'s 16 channel values are
// k-contiguous (kb = h*2+(w>>1), col = (w&1)*16+dd) -> 2 uint4 stores.
// ---------------------------------------------------------------------------
__global__ __launch_bounds__(256) void natt2(
    const unsigned short* __restrict__ qkv,  // (4,1536,3136) bf16
    unsigned short* __restrict__ aoT)        // [4][49][16][64][32] bf16
{
    __shared__ __align__(16) unsigned short smem[2 * 64 * SLEN]; // Kl | Vl
    unsigned short* Kl = smem;
    unsigned short* Vl = smem + 64 * SLEN;
    float* dred = reinterpret_cast<float*>(smem);  // overlays Kl after dots

    const int t = threadIdx.x, lane = t & 63, w = t >> 6;
    const int sblk = blockIdx.x;
    const int s0 = sblk * 64;
    const int s  = s0 + lane;
    const int h  = blockIdx.y, b = blockIdx.z;
    const int y  = s / WIMG, xx = s % WIMG;

    const size_t hbase = (size_t)b * QKV_CH * HW + (size_t)(h * 64) * HW;
    const unsigned short* kg = qkv + hbase + (size_t)512 * HW;
    const unsigned short* vg = qkv + hbase + (size_t)1024 * HW;

#pragma unroll
    for (int i = 0; i < 6; i++) {
        const int f = i * 256 + t;        // 0..1535
        const int d = f / 24, j = f % 24;
        int g = s0 - 64 + j * 8;
        g = min(max(g, 0), HW - 8);       // clamped slots only read by masked taps
        const uint4 k4 = *reinterpret_cast<const uint4*>(kg + (size_t)d * HW + g);
        const uint4 v4 = *reinterpret_cast<const uint4*>(vg + (size_t)d * HW + g);
        *reinterpret_cast<uint4*>(&Kl[d * SLEN + j * 8]) = k4;
        *reinterpret_cast<uint4*>(&Vl[d * SLEN + j * 8]) = v4;
    }

    int   off9[9];
    float msk[9];
#pragma unroll
    for (int ty = 0; ty < 3; ty++)
#pragma unroll
        for (int tx = 0; tx < 3; tx++) {
            const int tap = ty * 3 + tx;
            const int ny = y + ty - 1, nx = xx + tx - 1;
            const bool v = (ny >= 0) && (ny < WIMG) && (nx >= 0) && (nx < WIMG);
            off9[tap] = v ? ((ty - 1) * WIMG + (tx - 1)) : 0;
            msk[tap]  = v ? 1.f : 0.f;
        }

    __syncthreads();

    const unsigned short* qp = qkv + hbase + s;
    float dots[9];
#pragma unroll
    for (int tp = 0; tp < 9; tp++) dots[tp] = 0.f;
#pragma unroll 4
    for (int dd = 0; dd < 16; dd++) {
        const int d = w * 16 + dd;
        const float qv = bf2f(qp[(size_t)d * HW]);
        const int bi = d * SLEN + lane + 64;
#pragma unroll
        for (int tp = 0; tp < 9; tp++)
            dots[tp] += qv * bf2f(Kl[bi + off9[tp]]);
    }

    __syncthreads();
#pragma unroll
    for (int tp = 0; tp < 9; tp++) dred[(tp * 4 + w) * 64 + lane] = dots[tp];
    __syncthreads();

    float mx = -1e30f, dt[9];
#pragma unroll
    for (int tp = 0; tp < 9; tp++) {
        const float sum = dred[(tp * 4 + 0) * 64 + lane] + dred[(tp * 4 + 1) * 64 + lane] +
                          dred[(tp * 4 + 2) * 64 + lane] + dred[(tp * 4 + 3) * 64 + lane];
        dt[tp] = msk[tp] * (sum * SCALE);
        mx = fmaxf(mx, dt[tp]);
    }
    float se = 0.f, w9[9];
#pragma unroll
    for (int tp = 0; tp < 9; tp++) { w9[tp] = __expf(dt[tp] - mx); se += w9[tp]; }
    const float inv = 1.f / se;
#pragma unroll
    for (int tp = 0; tp < 9; tp++) w9[tp] *= inv * msk[tp];

    __align__(16) unsigned short ov[16];
#pragma unroll 4
    for (int dd = 0; dd < 16; dd++) {
        const int d = w * 16 + dd;
        const int bi = d * SLEN + lane + 64;
        float o = 0.f;
#pragma unroll
        for (int tp = 0; tp < 9; tp++)
            o += w9[tp] * bf2f(Vl[bi + off9[tp]]);
        ov[dd] = f2bf(o);
    }
    // blocked store: tile (b, sblk, kb=h*2+(w>>1)), row=lane, col=(w&1)*16
    unsigned short* dst = aoT + (((size_t)(b * 49 + sblk)) * 16 + (h * 2 + (w >> 1))) * 2048
                        + lane * 32 + (w & 1) * 16;
    *reinterpret_cast<uint4*>(dst)     = *reinterpret_cast<const uint4*>(ov);
    *reinterpret_cast<uint4*>(dst + 8) = *reinterpret_cast<const uint4*>(ov + 8);
}

// ---------------------------------------------------------------------------
// GEMM3 v2: out[b][o][s] = sum_c Wo[o][c]*ao[c][s] + bo[o]. Tile 128o x 64s,
// BK=32, identity uint4 staging from blocked aoT/wT3, 8 MFMA/wave/K-step.
// grid (49, 3, 4). Per-output K-order identical to old gemm3 -> bit-exact.
// ---------------------------------------------------------------------------
__global__ __launch_bounds__(256) void gemm3(
    const unsigned short* __restrict__ aoT,  // [4][49][16][64][32]
    const unsigned short* __restrict__ wT3,  // [3][16][128][32]
    const float* __restrict__ bias,          // (384)
    float* __restrict__ out)                 // (4,384,3136) f32
{
    __shared__ __align__(16) unsigned short A_lds[128 * 32];
    __shared__ __align__(16) unsigned short B_lds[64 * 32];

    const int sblk = blockIdx.x;             // 0..48
    const int oblk = blockIdx.y;             // 0..2
    const int b  = blockIdx.z;
    const int t  = threadIdx.x;
    const int lane = t & 63, w = t >> 6;
    const int quad = lane >> 4, mrow = lane & 15;
    const int wm = w >> 1, wn = w & 1;       // wave: 64o x 32s quadrant

    const unsigned short* asrc = wT3 + (size_t)oblk * 16 * 4096;
    const unsigned short* bsrc = aoT + ((size_t)(b * 49 + sblk)) * 16 * 2048;

    f32x4_t acc[4][2];
#pragma unroll
    for (int m = 0; m < 4; m++)
#pragma unroll
        for (int n = 0; n < 2; n++) acc[m][n] = (f32x4_t){0.f, 0.f, 0.f, 0.f};

    for (int kb = 0; kb < 16; kb++) {
        const uint4 a0 = *reinterpret_cast<const uint4*>(asrc + (size_t)kb * 4096 + t * 8);
        const uint4 a1 = *reinterpret_cast<const uint4*>(asrc + (size_t)kb * 4096 + 2048 + t * 8);
        const uint4 b0 = *reinterpret_cast<const uint4*>(bsrc + (size_t)kb * 2048 + t * 8);

        __syncthreads();
        *reinterpret_cast<uint4*>(A_lds + t * 8) = a0;
        *reinterpret_cast<uint4*>(A_lds + 2048 + t * 8) = a1;
        *reinterpret_cast<uint4*>(B_lds + t * 8) = b0;
        __syncthreads();

        bf16x8_t af[4], bf[2];
#pragma unroll
        for (int m = 0; m < 4; m++)
            af[m] = *reinterpret_cast<const bf16x8_t*>(&A_lds[(wm * 64 + m * 16 + mrow) * 32 + quad * 8]);
#pragma unroll
        for (int n = 0; n < 2; n++)
            bf[n] = *reinterpret_cast<const bf16x8_t*>(&B_lds[(wn * 32 + n * 16 + mrow) * 32 + quad * 8]);
#pragma unroll
        for (int m = 0; m < 4; m++)
#pragma unroll
            for (int n = 0; n < 2; n++)
                acc[m][n] = __builtin_amdgcn_mfma_f32_16x16x32_bf16(af[m], bf[n], acc[m][n], 0, 0, 0);
    }

    const int o0 = oblk * 128 + wm * 64;
    const int s0 = sblk * 64 + wn * 32;
    float* outb = out + (size_t)b * 384 * HW;
#pragma unroll
    for (int m = 0; m < 4; m++)
#pragma unroll
        for (int n = 0; n < 2; n++) {
            const int ss = s0 + n * 16 + mrow;      // < 3136 always (49*64 exact)
#pragma unroll
            for (int r = 0; r < 4; r++) {
                const int oo = o0 + m * 16 + quad * 4 + r;
                outb[(size_t)oo * HW + ss] = acc[m][n][r] + bias[oo];
            }
        }
}

extern "C" void kernel_launch(void* const* d_in, const int* in_sizes, int n_in,
                              void* d_out, int out_size, void* d_ws, size_t ws_size,
                              hipStream_t stream) {
    const float* x   = (const float*)d_in[0];
    const float* Wq  = (const float*)d_in[1];
    const float* Wkv = (const float*)d_in[2];
    const float* Wo  = (const float*)d_in[3];
    const float* bo  = (const float*)d_in[4];
    float* out = (float*)d_out;

    // ws layout (bf16 elements)
    unsigned short* xT   = (unsigned short*)d_ws;                 // 4*25*12*4096 = 4,915,200
    unsigned short* wT   = xT + (size_t)4915200;                  // 12*12*128*32 =   589,824
    unsigned short* wT3  = wT + (size_t)589824;                   // 3*16*128*32  =   196,608
    unsigned short* qkvb = wT3 + (size_t)196608;                  // 4*1536*3136  = 19,267,584
    unsigned short* aoT  = qkvb + (size_t)4 * QKV_CH * HW;        // 4*49*16*2048 =  6,422,528

    cvt_w<<<dim3(384), 256, 0, stream>>>(Wq, Wkv, Wo, wT, wT3);   // exact: 98304 threads
    cvtT_x<<<dim3(50, 12, 4), 256, 0, stream>>>(x, xT);

    gemm1<<<dim3(25, 12, 4), 256, 0, stream>>>(xT, wT, qkvb);
    natt2<<<dim3(49, 8, 4), 256, 0, stream>>>(qkvb, aoT);
    gemm3<<<dim3(49, 3, 4), 256, 0, stream>>>(aoT, wT3, bo, out);
}